// Round 2
// baseline (1410.029 us; speedup 1.0000x reference)
//
#include <hip/hip_runtime.h>
#include <math.h>

#define B_GROUPS 64
#define C_DIM 256
#define IN_DIM 512
#define EMB_DIM 512
#define NHEADS 8
#define HDIM 32

// ---------------- per-group starts via binary search ----------------
__global__ void starts_kernel(const int* __restrict__ bx, int nx,
                              const int* __restrict__ be, int ne,
                              int* __restrict__ sx, int* __restrict__ se) {
  int b = threadIdx.x;
  if (b > B_GROUPS) return;
  int lo = 0, hi = nx;
  while (lo < hi) { int mid = (lo + hi) >> 1; if (bx[mid] < b) lo = mid + 1; else hi = mid; }
  sx[b] = lo;
  lo = 0; hi = ne;
  while (lo < hi) { int mid = (lo + hi) >> 1; if (be[mid] < b) lo = mid + 1; else hi = mid; }
  se[b] = lo;
}

// ---------------- generic fp32 tiled GEMM: C = act(A@W + bias) ----------------
template<int ACT>
__global__ __launch_bounds__(256) void gemm_kernel(const float* __restrict__ A,
    const float* __restrict__ W, const float* __restrict__ bias,
    float* __restrict__ C, int M, int N, int K) {
  const int BM = 64, BN = 64, BK = 16;
  __shared__ float As[BK][68];
  __shared__ float Ws[BK][BN];
  int bm = blockIdx.y * BM, bn = blockIdx.x * BN;
  int tid = threadIdx.x;
  int tx = tid & 15, ty = tid >> 4;
  float acc[4][4] = {};
  for (int k0 = 0; k0 < K; k0 += BK) {
    {
      int r = tid >> 2;
      int c = (tid & 3) * 4;
      int gr = bm + r;
      float4 av = make_float4(0.f, 0.f, 0.f, 0.f);
      if (gr < M) av = *(const float4*)&A[(size_t)gr * K + k0 + c];
      As[c + 0][r] = av.x; As[c + 1][r] = av.y; As[c + 2][r] = av.z; As[c + 3][r] = av.w;
    }
    {
      int r = tid >> 4;
      int c = (tid & 15) * 4;
      float4 wv = *(const float4*)&W[(size_t)(k0 + r) * N + bn + c];
      *(float4*)&Ws[r][c] = wv;
    }
    __syncthreads();
#pragma unroll
    for (int kk = 0; kk < BK; ++kk) {
      float a[4], w[4];
#pragma unroll
      for (int i = 0; i < 4; ++i) a[i] = As[kk][ty * 4 + i];
#pragma unroll
      for (int i = 0; i < 4; ++i) w[i] = Ws[kk][tx * 4 + i];
#pragma unroll
      for (int i = 0; i < 4; ++i)
#pragma unroll
        for (int j = 0; j < 4; ++j) acc[i][j] += a[i] * w[j];
    }
    __syncthreads();
  }
#pragma unroll
  for (int i = 0; i < 4; ++i) {
    int gr = bm + ty * 4 + i;
    if (gr >= M) continue;
#pragma unroll
    for (int j = 0; j < 4; ++j) {
      int gc = bn + tx * 4 + j;
      float v = acc[i][j] + bias[gc];
      if (ACT == 1) v = 0.5f * v * (1.0f + erff(v * 0.70710678118654752f));
      C[(size_t)gr * N + gc] = v;
    }
  }
}

// ---------------- LayerNorm over last dim (256), in-place ----------------
__global__ __launch_bounds__(256) void ln_kernel(float* __restrict__ h,
    const float* __restrict__ w, const float* __restrict__ b, int M) {
  int row = blockIdx.x * 4 + (threadIdx.x >> 6);
  int lane = threadIdx.x & 63;
  if (row >= M) return;
  float4 v = *(const float4*)&h[(size_t)row * C_DIM + lane * 4];
  float s  = v.x + v.y + v.z + v.w;
  float s2 = v.x * v.x + v.y * v.y + v.z * v.z + v.w * v.w;
#pragma unroll
  for (int off = 1; off < 64; off <<= 1) { s += __shfl_xor(s, off); s2 += __shfl_xor(s2, off); }
  float mu  = s  * (1.0f / 256.0f);
  float var = s2 * (1.0f / 256.0f) - mu * mu;
  float inv = rsqrtf(var + 1e-5f);
  float4 wv = *(const float4*)&w[lane * 4];
  float4 bv = *(const float4*)&b[lane * 4];
  float4 o;
  o.x = (v.x - mu) * inv * wv.x + bv.x;
  o.y = (v.y - mu) * inv * wv.y + bv.y;
  o.z = (v.z - mu) * inv * wv.z + bv.z;
  o.w = (v.w - mu) * inv * wv.w + bv.w;
  *(float4*)&h[(size_t)row * C_DIM + lane * 4] = o;
}

// ---------------- ragged masked flash attention (v3) ----------------
// 1D grid 4096, XCD-swizzled so all 8 q-tiles of one (b,hd) share an XCD
// (K/V slice ~96KB -> L2-resident, fetched once instead of 6x).
// Thread (qg=tid>>3, j=tid&7): owns q-rows {qg, qg+32}, score cols {8t+j}.
// K,V stored row-major [64][36]; both QK^T and PV reads have 16B-position
// (j + chunk) mod 8 -> conflict-free, compile-time ds offsets.
// P never touches LDS: per-lane partial acc[2][32] over the lane's 8 cols,
// cross-lane butterfly reduce (xor 1,2,4) once at the end.
// ALL register arrays are fully unrolled / compile-time indexed (rule #20:
// v2's "#pragma unroll 4" sent qreg to scratch -> 400MB of scratch traffic).
__global__ __launch_bounds__(256) void attn_kernel(const float* __restrict__ q,
    const float* __restrict__ k, const float* __restrict__ v,
    const int* __restrict__ sx, const int* __restrict__ se,
    const int* __restrict__ emask, float* __restrict__ y) {
  int bid = blockIdx.x;
  int work = ((bid & 7) << 9) + (bid >> 3);   // same (b,hd) -> same XCD
  int qt = work & 7;
  int bh = work >> 3;
  int b  = bh & 63;
  int hd = bh >> 6;

  int xs = sx[b], lx = sx[b + 1] - xs;
  if (qt * 64 >= lx) return;
  int es = se[b], le = se[b + 1] - es;

  __shared__ float Ks[64][36];
  __shared__ float Vs[64][36];
  __shared__ int   Mk[64];

  int tid = threadIdx.x;
  int j  = tid & 7;
  int qg = tid >> 3;

  float qreg[2][32];
#pragma unroll
  for (int rr = 0; rr < 2; ++rr) {
    int qr = qt * 64 + qg + rr * 32;
    bool ok = qr < lx;
    const float* qp = &q[(size_t)(xs + qr) * C_DIM + hd * HDIM];
#pragma unroll
    for (int d4 = 0; d4 < 8; ++d4) {
      float4 t4 = ok ? *(const float4*)&qp[d4 * 4] : make_float4(0.f, 0.f, 0.f, 0.f);
      qreg[rr][d4 * 4 + 0] = t4.x; qreg[rr][d4 * 4 + 1] = t4.y;
      qreg[rr][d4 * 4 + 2] = t4.z; qreg[rr][d4 * 4 + 3] = t4.w;
    }
  }

  float acc[2][32] = {};
  float mrun[2] = {-INFINITY, -INFINITY};
  float lrun[2] = {0.f, 0.f};
  const float scale = 0.17677669529663689f;  // 1/sqrt(32)

  for (int kc = 0; kc < le; kc += 64) {
    int nk = le - kc; if (nk > 64) nk = 64;
    {
      int r = tid >> 3, c = (tid & 7) * 4;
#pragma unroll
      for (int it = 0; it < 2; ++it) {
        int rr = r + it * 32;
        float4 kv = make_float4(0.f, 0.f, 0.f, 0.f);
        float4 vv = make_float4(0.f, 0.f, 0.f, 0.f);
        if (rr < nk) {
          size_t base = (size_t)(es + kc + rr) * C_DIM + hd * HDIM + c;
          kv = *(const float4*)&k[base];
          vv = *(const float4*)&v[base];
        }
        *(float4*)&Ks[rr][c] = kv;
        *(float4*)&Vs[rr][c] = vv;
      }
      if (tid < 64) Mk[tid] = (tid < nk) ? emask[es + kc + tid] : 0;
    }
    __syncthreads();

    // ---- QK^T: p[r][t] = q_row_r . K[8t+j]
    float p[2][8] = {};
#pragma unroll
    for (int t = 0; t < 8; ++t) {
      const float* krow = &Ks[t * 8 + j][0];
#pragma unroll
      for (int d4 = 0; d4 < 8; ++d4) {
        float4 kv = *(const float4*)&krow[d4 * 4];
        p[0][t] += qreg[0][d4 * 4 + 0] * kv.x + qreg[0][d4 * 4 + 1] * kv.y
                 + qreg[0][d4 * 4 + 2] * kv.z + qreg[0][d4 * 4 + 3] * kv.w;
        p[1][t] += qreg[1][d4 * 4 + 0] * kv.x + qreg[1][d4 * 4 + 1] * kv.y
                 + qreg[1][d4 * 4 + 2] * kv.z + qreg[1][d4 * 4 + 3] * kv.w;
      }
    }

    int mk[8];
#pragma unroll
    for (int t = 0; t < 8; ++t) mk[t] = Mk[t * 8 + j];

    // ---- online softmax (8 j-lanes per row cooperate via shfl_xor 1,2,4)
    float alpha[2];
#pragma unroll
    for (int r = 0; r < 2; ++r) {
      float mloc = -INFINITY;
#pragma unroll
      for (int t = 0; t < 8; ++t) {
        float s = mk[t] ? p[r][t] * scale : -INFINITY;
        p[r][t] = s;
        mloc = fmaxf(mloc, s);
      }
      mloc = fmaxf(mloc, __shfl_xor(mloc, 1));
      mloc = fmaxf(mloc, __shfl_xor(mloc, 2));
      mloc = fmaxf(mloc, __shfl_xor(mloc, 4));
      float mnew = fmaxf(mrun[r], mloc);
      alpha[r] = (mnew == -INFINITY) ? 1.0f : __expf(mrun[r] - mnew);
      float lloc = 0.f;
#pragma unroll
      for (int t = 0; t < 8; ++t) {
        float pe = (p[r][t] == -INFINITY) ? 0.f : __expf(p[r][t] - mnew);
        p[r][t] = pe;
        lloc += pe;
      }
      lloc += __shfl_xor(lloc, 1);
      lloc += __shfl_xor(lloc, 2);
      lloc += __shfl_xor(lloc, 4);
      lrun[r] = lrun[r] * alpha[r] + lloc;
      mrun[r] = mnew;
    }

#pragma unroll
    for (int r = 0; r < 2; ++r)
#pragma unroll
      for (int d = 0; d < 32; ++d) acc[r][d] *= alpha[r];

    // ---- PV: acc[r][:] += sum_t p[r][t] * V[8t+j][:]
#pragma unroll
    for (int t = 0; t < 8; ++t) {
      float pa = p[0][t], pb = p[1][t];
      const float* vrow = &Vs[t * 8 + j][0];
#pragma unroll
      for (int c4 = 0; c4 < 8; ++c4) {
        float4 vv = *(const float4*)&vrow[c4 * 4];
        acc[0][c4 * 4 + 0] += pa * vv.x; acc[0][c4 * 4 + 1] += pa * vv.y;
        acc[0][c4 * 4 + 2] += pa * vv.z; acc[0][c4 * 4 + 3] += pa * vv.w;
        acc[1][c4 * 4 + 0] += pb * vv.x; acc[1][c4 * 4 + 1] += pb * vv.y;
        acc[1][c4 * 4 + 2] += pb * vv.z; acc[1][c4 * 4 + 3] += pb * vv.w;
      }
    }
    __syncthreads();
  }

  // ---- reduce partial sums across the 8 j-lanes of each row
#pragma unroll
  for (int r = 0; r < 2; ++r)
#pragma unroll
    for (int d = 0; d < 32; ++d) {
      float s = acc[r][d];
      s += __shfl_xor(s, 1);
      s += __shfl_xor(s, 2);
      s += __shfl_xor(s, 4);
      acc[r][d] = s;
    }

#pragma unroll
  for (int r = 0; r < 2; ++r) {
    int qr = qt * 64 + qg + r * 32;
    if (qr >= lx) continue;
    float invl = (lrun[r] > 0.f) ? 1.0f / lrun[r] : 0.f;
    float4 o = make_float4(0.f, 0.f, 0.f, 0.f);
#pragma unroll
    for (int c4 = 0; c4 < 8; ++c4) {
      if (j == c4) {   // compile-time acc indices, per-lane predicated pick
        o.x = acc[r][c4 * 4 + 0]; o.y = acc[r][c4 * 4 + 1];
        o.z = acc[r][c4 * 4 + 2]; o.w = acc[r][c4 * 4 + 3];
      }
    }
    o.x *= invl; o.y *= invl; o.z *= invl; o.w *= invl;
    *(float4*)&y[(size_t)(xs + qr) * C_DIM + hd * HDIM + j * 4] = o;
  }
}

// ---------------- launch ----------------
extern "C" void kernel_launch(void* const* d_in, const int* in_sizes, int n_in,
                              void* d_out, int out_size, void* d_ws, size_t ws_size,
                              hipStream_t stream) {
  const float* x    = (const float*)d_in[0];
  const int*   bx   = (const int*)d_in[1];
  const int*   be   = (const int*)d_in[2];
  const float* enc  = (const float*)d_in[3];
  const int*   msk  = (const int*)d_in[4];
  const float* Wq   = (const float*)d_in[5];
  const float* bq   = (const float*)d_in[6];
  const float* Wk   = (const float*)d_in[7];
  const float* bk   = (const float*)d_in[8];
  const float* Wv   = (const float*)d_in[9];
  const float* bv   = (const float*)d_in[10];
  const float* Wp   = (const float*)d_in[11];
  const float* bp   = (const float*)d_in[12];
  const float* W1   = (const float*)d_in[13];
  const float* b1   = (const float*)d_in[14];
  const float* W2   = (const float*)d_in[15];
  const float* b2   = (const float*)d_in[16];
  const float* lnw  = (const float*)d_in[17];
  const float* lnb  = (const float*)d_in[18];
  float* out = (float*)d_out;

  int Nx = in_sizes[0] / C_DIM;
  int Ne = in_sizes[3] / IN_DIM;
  int maxN = Nx > Ne ? Nx : Ne;

  char* ws = (char*)d_ws;
  int* sx = (int*)ws;          // 65 ints
  int* se = sx + 80;           // 65 ints
  float* R0 = (float*)(ws + 4096);              // Ne*512 floats (g, later k|v)
  float* g    = R0;
  float* kbuf = R0;
  float* vbuf = R0 + (size_t)Ne * C_DIM;
  float* R1 = R0 + (size_t)Ne * EMB_DIM;        // maxN*256 floats (h, later y)
  float* h    = R1;
  float* ybuf = R1;
  float* qbuf = R1 + (size_t)maxN * C_DIM;      // Nx*256 floats

  starts_kernel<<<1, 128, 0, stream>>>(bx, Nx, be, Ne, sx, se);

  // MLP: g = GELU(enc @ W1 + b1)   [Ne,512]
  gemm_kernel<1><<<dim3(EMB_DIM / 64, (Ne + 63) / 64), 256, 0, stream>>>(
      enc, W1, b1, g, Ne, EMB_DIM, IN_DIM);
  // h = g @ W2 + b2  [Ne,256], then LN
  gemm_kernel<0><<<dim3(C_DIM / 64, (Ne + 63) / 64), 256, 0, stream>>>(
      g, W2, b2, h, Ne, C_DIM, EMB_DIM);
  ln_kernel<<<(Ne + 3) / 4, 256, 0, stream>>>(h, lnw, lnb, Ne);

  // q = x @ Wq + bq ; k = h @ Wk + bk ; v = h @ Wv + bv
  gemm_kernel<0><<<dim3(C_DIM / 64, (Nx + 63) / 64), 256, 0, stream>>>(
      x, Wq, bq, qbuf, Nx, C_DIM, C_DIM);
  gemm_kernel<0><<<dim3(C_DIM / 64, (Ne + 63) / 64), 256, 0, stream>>>(
      h, Wk, bk, kbuf, Ne, C_DIM, C_DIM);
  gemm_kernel<0><<<dim3(C_DIM / 64, (Ne + 63) / 64), 256, 0, stream>>>(
      h, Wv, bv, vbuf, Ne, C_DIM, C_DIM);

  // attention -> ybuf (overwrites h region; h dead after k,v)
  attn_kernel<<<dim3(4096), 256, 0, stream>>>(
      qbuf, kbuf, vbuf, sx, se, msk, ybuf);

  // out = y @ Wp + bp
  gemm_kernel<0><<<dim3(C_DIM / 64, (Nx + 63) / 64), 256, 0, stream>>>(
      ybuf, Wp, bp, out, Nx, C_DIM, C_DIM);
}

// Round 3
// 1008.342 us; speedup vs baseline: 1.3984x; 1.3984x over previous
//
#include <hip/hip_runtime.h>
#include <math.h>

#define B_GROUPS 64
#define C_DIM 256
#define IN_DIM 512
#define EMB_DIM 512
#define NHEADS 8
#define HDIM 32

// ---------------- per-group starts via binary search ----------------
__global__ void starts_kernel(const int* __restrict__ bx, int nx,
                              const int* __restrict__ be, int ne,
                              int* __restrict__ sx, int* __restrict__ se) {
  int b = threadIdx.x;
  if (b > B_GROUPS) return;
  int lo = 0, hi = nx;
  while (lo < hi) { int mid = (lo + hi) >> 1; if (bx[mid] < b) lo = mid + 1; else hi = mid; }
  sx[b] = lo;
  lo = 0; hi = ne;
  while (lo < hi) { int mid = (lo + hi) >> 1; if (be[mid] < b) lo = mid + 1; else hi = mid; }
  se[b] = lo;
}

// ---------------- generic fp32 tiled GEMM: C = act(A@W + bias) ----------------
template<int ACT>
__global__ __launch_bounds__(256) void gemm_kernel(const float* __restrict__ A,
    const float* __restrict__ W, const float* __restrict__ bias,
    float* __restrict__ C, int M, int N, int K) {
  const int BM = 64, BN = 64, BK = 16;
  __shared__ float As[BK][68];
  __shared__ float Ws[BK][BN];
  int bm = blockIdx.y * BM, bn = blockIdx.x * BN;
  int tid = threadIdx.x;
  int tx = tid & 15, ty = tid >> 4;
  float acc[4][4] = {};
  for (int k0 = 0; k0 < K; k0 += BK) {
    {
      int r = tid >> 2;
      int c = (tid & 3) * 4;
      int gr = bm + r;
      float4 av = make_float4(0.f, 0.f, 0.f, 0.f);
      if (gr < M) av = *(const float4*)&A[(size_t)gr * K + k0 + c];
      As[c + 0][r] = av.x; As[c + 1][r] = av.y; As[c + 2][r] = av.z; As[c + 3][r] = av.w;
    }
    {
      int r = tid >> 4;
      int c = (tid & 15) * 4;
      float4 wv = *(const float4*)&W[(size_t)(k0 + r) * N + bn + c];
      *(float4*)&Ws[r][c] = wv;
    }
    __syncthreads();
#pragma unroll
    for (int kk = 0; kk < BK; ++kk) {
      float a[4], w[4];
#pragma unroll
      for (int i = 0; i < 4; ++i) a[i] = As[kk][ty * 4 + i];
#pragma unroll
      for (int i = 0; i < 4; ++i) w[i] = Ws[kk][tx * 4 + i];
#pragma unroll
      for (int i = 0; i < 4; ++i)
#pragma unroll
        for (int j = 0; j < 4; ++j) acc[i][j] += a[i] * w[j];
    }
    __syncthreads();
  }
#pragma unroll
  for (int i = 0; i < 4; ++i) {
    int gr = bm + ty * 4 + i;
    if (gr >= M) continue;
#pragma unroll
    for (int j = 0; j < 4; ++j) {
      int gc = bn + tx * 4 + j;
      float v = acc[i][j] + bias[gc];
      if (ACT == 1) v = 0.5f * v * (1.0f + erff(v * 0.70710678118654752f));
      C[(size_t)gr * N + gc] = v;
    }
  }
}

// ---------------- LayerNorm over last dim (256), in-place ----------------
__global__ __launch_bounds__(256) void ln_kernel(float* __restrict__ h,
    const float* __restrict__ w, const float* __restrict__ b, int M) {
  int row = blockIdx.x * 4 + (threadIdx.x >> 6);
  int lane = threadIdx.x & 63;
  if (row >= M) return;
  float4 v = *(const float4*)&h[(size_t)row * C_DIM + lane * 4];
  float s  = v.x + v.y + v.z + v.w;
  float s2 = v.x * v.x + v.y * v.y + v.z * v.z + v.w * v.w;
#pragma unroll
  for (int off = 1; off < 64; off <<= 1) { s += __shfl_xor(s, off); s2 += __shfl_xor(s2, off); }
  float mu  = s  * (1.0f / 256.0f);
  float var = s2 * (1.0f / 256.0f) - mu * mu;
  float inv = rsqrtf(var + 1e-5f);
  float4 wv = *(const float4*)&w[lane * 4];
  float4 bv = *(const float4*)&b[lane * 4];
  float4 o;
  o.x = (v.x - mu) * inv * wv.x + bv.x;
  o.y = (v.y - mu) * inv * wv.y + bv.y;
  o.z = (v.z - mu) * inv * wv.z + bv.z;
  o.w = (v.w - mu) * inv * wv.w + bv.w;
  *(float4*)&h[(size_t)row * C_DIM + lane * 4] = o;
}

// ---------------- ragged masked flash attention (v4) ----------------
// = v2's register-frugal decomposition + v3's full unroll + XCD swizzle.
// 1D grid 4096, XCD-swizzled: all 8 q-tiles of one (b,hd) share an XCD
// (K/V slice ~96KB L2-resident: FETCH 852->55MB measured in v3).
// Thread (qg=tid>>3 in 0..31, j=tid&7): owns q-rows {qg,qg+32},
// score cols {8t+j, t=0..7}, value dims {j*4..j*4+3}.
// Per-thread persistent state: qreg[2][32] + acc[2][4] + p[2][8] ~ 90 floats
// (v3's acc[2][32] hit the 256-VGPR cliff and spilled 350MB to scratch).
// All register arrays compile-time indexed (rule #20).
// Bank behavior (32 banks x 4B):
//   Ks/Vs row-major [64][36]: QK^T reads rows 8t+j, stride 144B -> 16B-pos
//     9j mod 8 distinct; qg-lanes broadcast. Conflict-free.
//   Ps[64][68]: scalar writes bank=4qg+8t+j mod 32 -> exactly 2 lanes/bank
//     (free per m136); float4 reads pos 17*qg mod 8 distinct. Conflict-free.
__global__ __launch_bounds__(256) void attn_kernel(const float* __restrict__ q,
    const float* __restrict__ k, const float* __restrict__ v,
    const int* __restrict__ sx, const int* __restrict__ se,
    const int* __restrict__ emask, float* __restrict__ y) {
  int bid = blockIdx.x;
  int work = ((bid & 7) << 9) + (bid >> 3);   // same (b,hd) -> same XCD
  int qt = work & 7;
  int bh = work >> 3;
  int b  = bh & 63;
  int hd = bh >> 6;

  int xs = sx[b], lx = sx[b + 1] - xs;
  if (qt * 64 >= lx) return;
  int es = se[b], le = se[b + 1] - es;

  __shared__ float Ks[64][36];
  __shared__ float Vs[64][36];
  __shared__ float Ps[64][68];
  __shared__ int   Mk[64];

  int tid = threadIdx.x;
  int j  = tid & 7;
  int qg = tid >> 3;   // 0..31

  float qreg[2][32];
#pragma unroll
  for (int rr = 0; rr < 2; ++rr) {
    int qr = qt * 64 + qg + rr * 32;
    bool ok = qr < lx;
    const float* qp = &q[(size_t)(xs + qr) * C_DIM + hd * HDIM];
#pragma unroll
    for (int d4 = 0; d4 < 8; ++d4) {
      float4 t4 = ok ? *(const float4*)&qp[d4 * 4] : make_float4(0.f, 0.f, 0.f, 0.f);
      qreg[rr][d4 * 4 + 0] = t4.x; qreg[rr][d4 * 4 + 1] = t4.y;
      qreg[rr][d4 * 4 + 2] = t4.z; qreg[rr][d4 * 4 + 3] = t4.w;
    }
  }

  float acc[2][4] = {};
  float mrun[2] = {-INFINITY, -INFINITY};
  float lrun[2] = {0.f, 0.f};
  const float scale = 0.17677669529663689f;  // 1/sqrt(32)

  for (int kc = 0; kc < le; kc += 64) {
    int nk = le - kc; if (nk > 64) nk = 64;
    {
      int r = tid >> 3, c = (tid & 7) * 4;
#pragma unroll
      for (int it = 0; it < 2; ++it) {
        int rr = r + it * 32;
        float4 kv = make_float4(0.f, 0.f, 0.f, 0.f);
        float4 vv = make_float4(0.f, 0.f, 0.f, 0.f);
        if (rr < nk) {
          size_t base = (size_t)(es + kc + rr) * C_DIM + hd * HDIM + c;
          kv = *(const float4*)&k[base];
          vv = *(const float4*)&v[base];
        }
        *(float4*)&Ks[rr][c] = kv;
        *(float4*)&Vs[rr][c] = vv;
      }
      if (tid < 64) Mk[tid] = (tid < nk) ? emask[es + kc + tid] : 0;
    }
    __syncthreads();

    // ---- QK^T: p[r][t] = q_row_r . K[8t+j], fully unrolled
    float p[2][8] = {};
#pragma unroll
    for (int t = 0; t < 8; ++t) {
      const float* krow = &Ks[t * 8 + j][0];
#pragma unroll
      for (int d4 = 0; d4 < 8; ++d4) {
        float4 kv = *(const float4*)&krow[d4 * 4];
        p[0][t] += qreg[0][d4 * 4 + 0] * kv.x + qreg[0][d4 * 4 + 1] * kv.y
                 + qreg[0][d4 * 4 + 2] * kv.z + qreg[0][d4 * 4 + 3] * kv.w;
        p[1][t] += qreg[1][d4 * 4 + 0] * kv.x + qreg[1][d4 * 4 + 1] * kv.y
                 + qreg[1][d4 * 4 + 2] * kv.z + qreg[1][d4 * 4 + 3] * kv.w;
      }
    }

    int mk[8];
#pragma unroll
    for (int t = 0; t < 8; ++t) mk[t] = Mk[t * 8 + j];

    // ---- online softmax (8 j-lanes per q-row cooperate via shfl_xor 1,2,4)
    float alpha[2];
#pragma unroll
    for (int r = 0; r < 2; ++r) {
      float mloc = -INFINITY;
#pragma unroll
      for (int t = 0; t < 8; ++t) {
        float s = mk[t] ? p[r][t] * scale : -INFINITY;
        p[r][t] = s;
        mloc = fmaxf(mloc, s);
      }
      mloc = fmaxf(mloc, __shfl_xor(mloc, 1));
      mloc = fmaxf(mloc, __shfl_xor(mloc, 2));
      mloc = fmaxf(mloc, __shfl_xor(mloc, 4));
      float mnew = fmaxf(mrun[r], mloc);
      alpha[r] = (mnew == -INFINITY) ? 1.0f : __expf(mrun[r] - mnew);
      float lloc = 0.f;
#pragma unroll
      for (int t = 0; t < 8; ++t) {
        float pe = (p[r][t] == -INFINITY) ? 0.f : __expf(p[r][t] - mnew);
        p[r][t] = pe;
        lloc += pe;
      }
      lloc += __shfl_xor(lloc, 1);
      lloc += __shfl_xor(lloc, 2);
      lloc += __shfl_xor(lloc, 4);
      lrun[r] = lrun[r] * alpha[r] + lloc;
      mrun[r] = mnew;
    }

    // ---- P -> LDS (interleaved cols: lane j owns 8t+j)
#pragma unroll
    for (int t = 0; t < 8; ++t) {
      Ps[qg][t * 8 + j]      = p[0][t];
      Ps[qg + 32][t * 8 + j] = p[1][t];
    }
#pragma unroll
    for (int r = 0; r < 2; ++r)
#pragma unroll
      for (int d = 0; d < 4; ++d) acc[r][d] *= alpha[r];
    __syncthreads();

    // ---- PV: acc[r][d] = sum_kk Ps[row_r][kk] * Vs[kk][j*4+d]
#pragma unroll
    for (int kk4 = 0; kk4 < 16; ++kk4) {
      float pa[4], pb[4];
      *(float4*)pa = *(const float4*)&Ps[qg][kk4 * 4];
      *(float4*)pb = *(const float4*)&Ps[qg + 32][kk4 * 4];
#pragma unroll
      for (int u = 0; u < 4; ++u) {
        float4 vv = *(const float4*)&Vs[kk4 * 4 + u][j * 4];
        acc[0][0] += pa[u] * vv.x; acc[0][1] += pa[u] * vv.y;
        acc[0][2] += pa[u] * vv.z; acc[0][3] += pa[u] * vv.w;
        acc[1][0] += pb[u] * vv.x; acc[1][1] += pb[u] * vv.y;
        acc[1][2] += pb[u] * vv.z; acc[1][3] += pb[u] * vv.w;
      }
    }
    __syncthreads();
  }

#pragma unroll
  for (int r = 0; r < 2; ++r) {
    int qr = qt * 64 + qg + r * 32;
    if (qr >= lx) continue;
    float invl = (lrun[r] > 0.f) ? 1.0f / lrun[r] : 0.f;
    float4 o = make_float4(acc[r][0] * invl, acc[r][1] * invl,
                           acc[r][2] * invl, acc[r][3] * invl);
    *(float4*)&y[(size_t)(xs + qr) * C_DIM + hd * HDIM + j * 4] = o;
  }
}

// ---------------- launch ----------------
extern "C" void kernel_launch(void* const* d_in, const int* in_sizes, int n_in,
                              void* d_out, int out_size, void* d_ws, size_t ws_size,
                              hipStream_t stream) {
  const float* x    = (const float*)d_in[0];
  const int*   bx   = (const int*)d_in[1];
  const int*   be   = (const int*)d_in[2];
  const float* enc  = (const float*)d_in[3];
  const int*   msk  = (const int*)d_in[4];
  const float* Wq   = (const float*)d_in[5];
  const float* bq   = (const float*)d_in[6];
  const float* Wk   = (const float*)d_in[7];
  const float* bk   = (const float*)d_in[8];
  const float* Wv   = (const float*)d_in[9];
  const float* bv   = (const float*)d_in[10];
  const float* Wp   = (const float*)d_in[11];
  const float* bp   = (const float*)d_in[12];
  const float* W1   = (const float*)d_in[13];
  const float* b1   = (const float*)d_in[14];
  const float* W2   = (const float*)d_in[15];
  const float* b2   = (const float*)d_in[16];
  const float* lnw  = (const float*)d_in[17];
  const float* lnb  = (const float*)d_in[18];
  float* out = (float*)d_out;

  int Nx = in_sizes[0] / C_DIM;
  int Ne = in_sizes[3] / IN_DIM;
  int maxN = Nx > Ne ? Nx : Ne;

  char* ws = (char*)d_ws;
  int* sx = (int*)ws;          // 65 ints
  int* se = sx + 80;           // 65 ints
  float* R0 = (float*)(ws + 4096);              // Ne*512 floats (g, later k|v)
  float* g    = R0;
  float* kbuf = R0;
  float* vbuf = R0 + (size_t)Ne * C_DIM;
  float* R1 = R0 + (size_t)Ne * EMB_DIM;        // maxN*256 floats (h, later y)
  float* h    = R1;
  float* ybuf = R1;
  float* qbuf = R1 + (size_t)maxN * C_DIM;      // Nx*256 floats

  starts_kernel<<<1, 128, 0, stream>>>(bx, Nx, be, Ne, sx, se);

  // MLP: g = GELU(enc @ W1 + b1)   [Ne,512]
  gemm_kernel<1><<<dim3(EMB_DIM / 64, (Ne + 63) / 64), 256, 0, stream>>>(
      enc, W1, b1, g, Ne, EMB_DIM, IN_DIM);
  // h = g @ W2 + b2  [Ne,256], then LN
  gemm_kernel<0><<<dim3(C_DIM / 64, (Ne + 63) / 64), 256, 0, stream>>>(
      g, W2, b2, h, Ne, C_DIM, EMB_DIM);
  ln_kernel<<<(Ne + 3) / 4, 256, 0, stream>>>(h, lnw, lnb, Ne);

  // q = x @ Wq + bq ; k = h @ Wk + bk ; v = h @ Wv + bv
  gemm_kernel<0><<<dim3(C_DIM / 64, (Nx + 63) / 64), 256, 0, stream>>>(
      x, Wq, bq, qbuf, Nx, C_DIM, C_DIM);
  gemm_kernel<0><<<dim3(C_DIM / 64, (Ne + 63) / 64), 256, 0, stream>>>(
      h, Wk, bk, kbuf, Ne, C_DIM, C_DIM);
  gemm_kernel<0><<<dim3(C_DIM / 64, (Ne + 63) / 64), 256, 0, stream>>>(
      h, Wv, bv, vbuf, Ne, C_DIM, C_DIM);

  // attention -> ybuf (overwrites h region; h dead after k,v)
  attn_kernel<<<dim3(4096), 256, 0, stream>>>(
      qbuf, kbuf, vbuf, sx, se, msk, ybuf);

  // out = y @ Wp + bp
  gemm_kernel<0><<<dim3(C_DIM / 64, (Nx + 63) / 64), 256, 0, stream>>>(
      ybuf, Wp, bp, out, Nx, C_DIM, C_DIM);
}

// Round 4
// 774.362 us; speedup vs baseline: 1.8209x; 1.3022x over previous
//
#include <hip/hip_runtime.h>
#include <math.h>

#define B_GROUPS 64
#define C_DIM 256
#define IN_DIM 512
#define EMB_DIM 512
#define NHEADS 8
#define HDIM 32

// ---------------- per-group starts via binary search ----------------
__global__ void starts_kernel(const int* __restrict__ bx, int nx,
                              const int* __restrict__ be, int ne,
                              int* __restrict__ sx, int* __restrict__ se) {
  int b = threadIdx.x;
  if (b > B_GROUPS) return;
  int lo = 0, hi = nx;
  while (lo < hi) { int mid = (lo + hi) >> 1; if (bx[mid] < b) lo = mid + 1; else hi = mid; }
  sx[b] = lo;
  lo = 0; hi = ne;
  while (lo < hi) { int mid = (lo + hi) >> 1; if (be[mid] < b) lo = mid + 1; else hi = mid; }
  se[b] = lo;
}

// ---------------- generic fp32 tiled GEMM: C = act(A@W + bias) ----------------
template<int ACT>
__global__ __launch_bounds__(256) void gemm_kernel(const float* __restrict__ A,
    const float* __restrict__ W, const float* __restrict__ bias,
    float* __restrict__ C, int M, int N, int K) {
  const int BM = 64, BN = 64, BK = 16;
  __shared__ float As[BK][68];
  __shared__ float Ws[BK][BN];
  int bm = blockIdx.y * BM, bn = blockIdx.x * BN;
  int tid = threadIdx.x;
  int tx = tid & 15, ty = tid >> 4;
  float acc[4][4] = {};
  for (int k0 = 0; k0 < K; k0 += BK) {
    {
      int r = tid >> 2;
      int c = (tid & 3) * 4;
      int gr = bm + r;
      float4 av = make_float4(0.f, 0.f, 0.f, 0.f);
      if (gr < M) av = *(const float4*)&A[(size_t)gr * K + k0 + c];
      As[c + 0][r] = av.x; As[c + 1][r] = av.y; As[c + 2][r] = av.z; As[c + 3][r] = av.w;
    }
    {
      int r = tid >> 4;
      int c = (tid & 15) * 4;
      float4 wv = *(const float4*)&W[(size_t)(k0 + r) * N + bn + c];
      *(float4*)&Ws[r][c] = wv;
    }
    __syncthreads();
#pragma unroll
    for (int kk = 0; kk < BK; ++kk) {
      float a[4], w[4];
#pragma unroll
      for (int i = 0; i < 4; ++i) a[i] = As[kk][ty * 4 + i];
#pragma unroll
      for (int i = 0; i < 4; ++i) w[i] = Ws[kk][tx * 4 + i];
#pragma unroll
      for (int i = 0; i < 4; ++i)
#pragma unroll
        for (int j = 0; j < 4; ++j) acc[i][j] += a[i] * w[j];
    }
    __syncthreads();
  }
#pragma unroll
  for (int i = 0; i < 4; ++i) {
    int gr = bm + ty * 4 + i;
    if (gr >= M) continue;
#pragma unroll
    for (int j = 0; j < 4; ++j) {
      int gc = bn + tx * 4 + j;
      float v = acc[i][j] + bias[gc];
      if (ACT == 1) v = 0.5f * v * (1.0f + erff(v * 0.70710678118654752f));
      C[(size_t)gr * N + gc] = v;
    }
  }
}

// ---------------- LayerNorm over last dim (256), in-place ----------------
__global__ __launch_bounds__(256) void ln_kernel(float* __restrict__ h,
    const float* __restrict__ w, const float* __restrict__ b, int M) {
  int row = blockIdx.x * 4 + (threadIdx.x >> 6);
  int lane = threadIdx.x & 63;
  if (row >= M) return;
  float4 v = *(const float4*)&h[(size_t)row * C_DIM + lane * 4];
  float s  = v.x + v.y + v.z + v.w;
  float s2 = v.x * v.x + v.y * v.y + v.z * v.z + v.w * v.w;
#pragma unroll
  for (int off = 1; off < 64; off <<= 1) { s += __shfl_xor(s, off); s2 += __shfl_xor(s2, off); }
  float mu  = s  * (1.0f / 256.0f);
  float var = s2 * (1.0f / 256.0f) - mu * mu;
  float inv = rsqrtf(var + 1e-5f);
  float4 wv = *(const float4*)&w[lane * 4];
  float4 bv = *(const float4*)&b[lane * 4];
  float4 o;
  o.x = (v.x - mu) * inv * wv.x + bv.x;
  o.y = (v.y - mu) * inv * wv.y + bv.y;
  o.z = (v.z - mu) * inv * wv.z + bv.z;
  o.w = (v.w - mu) * inv * wv.w + bv.w;
  *(float4*)&h[(size_t)row * C_DIM + lane * 4] = o;
}

// ---------------- ragged masked flash attention (v5) ----------------
// OCCUPANCY version: 1 q-row/thread (qreg[32] -> ~half the persistent regs of
// v4's qreg[2][32] which compiled to 240 VGPR / 2 waves/SIMD / 9.6% occ).
// 32-row q-tiles, 16 tiles per (b,hd), grid 8192, launch_bounds(256,4):
// cap 128 VGPR -> 4 waves/SIMD; LDS 27.4KB -> 5 blocks/CU; target occ ~50%.
// Thread (qg=tid>>3 in 0..31, j=tid&7): owns q-row qg, score cols {8t+j},
// value dims {j*4..j*4+3}. All register arrays compile-time indexed.
// Mask as additive bias row Bs[64] (0 / -1e30): no int regs, no branches;
// padded rows -> exp->0; transient all-masked tile self-heals (next valid
// tile's alpha=exp(-1e30-m)=0 resets l,acc).
// Bank behavior: K reads granule (j+d4)&7 distinct, qg-broadcast; V reads
// 8 distinct granules, qg-broadcast; Ps[32][68] reads 4-way on 16 instrs
// (~free per m136). Only 2 barriers/tile (Ks/Vs staging); Ps write->read is
// same-wave RAW (lgkmcnt-ordered, no barrier needed).
__global__ __launch_bounds__(256, 4) void attn_kernel(const float* __restrict__ q,
    const float* __restrict__ k, const float* __restrict__ v,
    const int* __restrict__ sx, const int* __restrict__ se,
    const int* __restrict__ emask, float* __restrict__ y) {
  int bid = blockIdx.x;
  int work = ((bid & 7) << 10) + (bid >> 3);   // same (b,hd) -> same XCD
  int qt = work & 15;
  int bh = work >> 4;
  int b  = bh & 63;
  int hd = bh >> 6;

  int xs = sx[b], lx = sx[b + 1] - xs;
  if (qt * 32 >= lx) return;
  int es = se[b], le = se[b + 1] - es;

  __shared__ float Ks[64][36];
  __shared__ float Vs[64][36];
  __shared__ float Ps[32][68];
  __shared__ float Bs[64];

  int tid = threadIdx.x;
  int j  = tid & 7;
  int qg = tid >> 3;   // 0..31

  int qr = qt * 32 + qg;
  bool qok = qr < lx;
  float qreg[32];
  {
    const float* qp = &q[(size_t)(xs + (qok ? qr : 0)) * C_DIM + hd * HDIM];
#pragma unroll
    for (int d4 = 0; d4 < 8; ++d4) {
      float4 t4 = *(const float4*)&qp[d4 * 4];
      qreg[d4 * 4 + 0] = t4.x; qreg[d4 * 4 + 1] = t4.y;
      qreg[d4 * 4 + 2] = t4.z; qreg[d4 * 4 + 3] = t4.w;
    }
  }

  float acc[4] = {};
  float mrun = -INFINITY, lrun = 0.f;
  const float scale = 0.17677669529663689f;  // 1/sqrt(32)

  for (int kc = 0; kc < le; kc += 64) {
    int nk = le - kc; if (nk > 64) nk = 64;
    {
      int r = tid >> 3, c = (tid & 7) * 4;
#pragma unroll
      for (int it = 0; it < 2; ++it) {
        int rr = r + it * 32;
        float4 kv = make_float4(0.f, 0.f, 0.f, 0.f);
        float4 vv = make_float4(0.f, 0.f, 0.f, 0.f);
        if (rr < nk) {
          size_t base = (size_t)(es + kc + rr) * C_DIM + hd * HDIM + c;
          kv = *(const float4*)&k[base];
          vv = *(const float4*)&v[base];
        }
        *(float4*)&Ks[rr][c] = kv;
        *(float4*)&Vs[rr][c] = vv;
      }
      if (tid < 64)
        Bs[tid] = (tid < nk && emask[es + kc + tid]) ? 0.f : -1e30f;
    }
    __syncthreads();

    // ---- QK^T: p[t] = qrow . K[8t+j], scaled + mask bias
    float bs[8];
#pragma unroll
    for (int t = 0; t < 8; ++t) bs[t] = Bs[t * 8 + j];

    float p[8];
#pragma unroll
    for (int t = 0; t < 8; ++t) {
      const float* krow = &Ks[t * 8 + j][0];
      float s = 0.f;
#pragma unroll
      for (int d4 = 0; d4 < 8; ++d4) {
        float4 kv = *(const float4*)&krow[d4 * 4];
        s += qreg[d4 * 4 + 0] * kv.x + qreg[d4 * 4 + 1] * kv.y
           + qreg[d4 * 4 + 2] * kv.z + qreg[d4 * 4 + 3] * kv.w;
      }
      p[t] = s * scale + bs[t];
    }

    // ---- online softmax (8 j-lanes per q-row cooperate via shfl_xor 1,2,4)
    float mloc = p[0];
#pragma unroll
    for (int t = 1; t < 8; ++t) mloc = fmaxf(mloc, p[t]);
    mloc = fmaxf(mloc, __shfl_xor(mloc, 1));
    mloc = fmaxf(mloc, __shfl_xor(mloc, 2));
    mloc = fmaxf(mloc, __shfl_xor(mloc, 4));
    float mnew = fmaxf(mrun, mloc);          // finite (Bs is -1e30, not -inf)
    float alpha = __expf(mrun - mnew);       // first tile: exp(-inf)=0
    float lloc = 0.f;
#pragma unroll
    for (int t = 0; t < 8; ++t) {
      float pe = __expf(p[t] - mnew);
      Ps[qg][t * 8 + j] = pe;
      lloc += pe;
    }
    lloc += __shfl_xor(lloc, 1);
    lloc += __shfl_xor(lloc, 2);
    lloc += __shfl_xor(lloc, 4);
    lrun = lrun * alpha + lloc;
    mrun = mnew;
#pragma unroll
    for (int d = 0; d < 4; ++d) acc[d] *= alpha;

    // ---- PV: acc[d] += sum_kk Ps[qg][kk] * Vs[kk][j*4+d]
    // (no barrier: Ps written/read by the same wave; Vs protected by the
    //  end-of-loop barrier before next staging)
#pragma unroll
    for (int kk4 = 0; kk4 < 16; ++kk4) {
      float pa[4];
      *(float4*)pa = *(const float4*)&Ps[qg][kk4 * 4];
#pragma unroll
      for (int u = 0; u < 4; ++u) {
        float4 vv = *(const float4*)&Vs[kk4 * 4 + u][j * 4];
        acc[0] += pa[u] * vv.x; acc[1] += pa[u] * vv.y;
        acc[2] += pa[u] * vv.z; acc[3] += pa[u] * vv.w;
      }
    }
    __syncthreads();
  }

  if (qok) {
    float invl = (lrun > 0.f) ? 1.0f / lrun : 0.f;
    float4 o = make_float4(acc[0] * invl, acc[1] * invl,
                           acc[2] * invl, acc[3] * invl);
    *(float4*)&y[(size_t)(xs + qr) * C_DIM + hd * HDIM + j * 4] = o;
  }
}

// ---------------- launch ----------------
extern "C" void kernel_launch(void* const* d_in, const int* in_sizes, int n_in,
                              void* d_out, int out_size, void* d_ws, size_t ws_size,
                              hipStream_t stream) {
  const float* x    = (const float*)d_in[0];
  const int*   bx   = (const int*)d_in[1];
  const int*   be   = (const int*)d_in[2];
  const float* enc  = (const float*)d_in[3];
  const int*   msk  = (const int*)d_in[4];
  const float* Wq   = (const float*)d_in[5];
  const float* bq   = (const float*)d_in[6];
  const float* Wk   = (const float*)d_in[7];
  const float* bk   = (const float*)d_in[8];
  const float* Wv   = (const float*)d_in[9];
  const float* bv   = (const float*)d_in[10];
  const float* Wp   = (const float*)d_in[11];
  const float* bp   = (const float*)d_in[12];
  const float* W1   = (const float*)d_in[13];
  const float* b1   = (const float*)d_in[14];
  const float* W2   = (const float*)d_in[15];
  const float* b2   = (const float*)d_in[16];
  const float* lnw  = (const float*)d_in[17];
  const float* lnb  = (const float*)d_in[18];
  float* out = (float*)d_out;

  int Nx = in_sizes[0] / C_DIM;
  int Ne = in_sizes[3] / IN_DIM;
  int maxN = Nx > Ne ? Nx : Ne;

  char* ws = (char*)d_ws;
  int* sx = (int*)ws;          // 65 ints
  int* se = sx + 80;           // 65 ints
  float* R0 = (float*)(ws + 4096);              // Ne*512 floats (g, later k|v)
  float* g    = R0;
  float* kbuf = R0;
  float* vbuf = R0 + (size_t)Ne * C_DIM;
  float* R1 = R0 + (size_t)Ne * EMB_DIM;        // maxN*256 floats (h, later y)
  float* h    = R1;
  float* ybuf = R1;
  float* qbuf = R1 + (size_t)maxN * C_DIM;      // Nx*256 floats

  starts_kernel<<<1, 128, 0, stream>>>(bx, Nx, be, Ne, sx, se);

  // MLP: g = GELU(enc @ W1 + b1)   [Ne,512]
  gemm_kernel<1><<<dim3(EMB_DIM / 64, (Ne + 63) / 64), 256, 0, stream>>>(
      enc, W1, b1, g, Ne, EMB_DIM, IN_DIM);
  // h = g @ W2 + b2  [Ne,256], then LN
  gemm_kernel<0><<<dim3(C_DIM / 64, (Ne + 63) / 64), 256, 0, stream>>>(
      g, W2, b2, h, Ne, C_DIM, EMB_DIM);
  ln_kernel<<<(Ne + 3) / 4, 256, 0, stream>>>(h, lnw, lnb, Ne);

  // q = x @ Wq + bq ; k = h @ Wk + bk ; v = h @ Wv + bv
  gemm_kernel<0><<<dim3(C_DIM / 64, (Nx + 63) / 64), 256, 0, stream>>>(
      x, Wq, bq, qbuf, Nx, C_DIM, C_DIM);
  gemm_kernel<0><<<dim3(C_DIM / 64, (Ne + 63) / 64), 256, 0, stream>>>(
      h, Wk, bk, kbuf, Ne, C_DIM, C_DIM);
  gemm_kernel<0><<<dim3(C_DIM / 64, (Ne + 63) / 64), 256, 0, stream>>>(
      h, Wv, bv, vbuf, Ne, C_DIM, C_DIM);

  // attention -> ybuf (overwrites h region; h dead after k,v)
  attn_kernel<<<dim3(8192), 256, 0, stream>>>(
      qbuf, kbuf, vbuf, sx, se, msk, ybuf);

  // out = y @ Wp + bp
  gemm_kernel<0><<<dim3(C_DIM / 64, (Nx + 63) / 64), 256, 0, stream>>>(
      ybuf, Wp, bp, out, Nx, C_DIM, C_DIM);
}

// Round 5
// 735.069 us; speedup vs baseline: 1.9182x; 1.0535x over previous
//
#include <hip/hip_runtime.h>
#include <math.h>

#define B_GROUPS 64
#define C_DIM 256
#define IN_DIM 512
#define EMB_DIM 512
#define NHEADS 8
#define HDIM 32

// ---------------- per-group starts via binary search ----------------
__global__ void starts_kernel(const int* __restrict__ bx, int nx,
                              const int* __restrict__ be, int ne,
                              int* __restrict__ sx, int* __restrict__ se) {
  int b = threadIdx.x;
  if (b > B_GROUPS) return;
  int lo = 0, hi = nx;
  while (lo < hi) { int mid = (lo + hi) >> 1; if (bx[mid] < b) lo = mid + 1; else hi = mid; }
  sx[b] = lo;
  lo = 0; hi = ne;
  while (lo < hi) { int mid = (lo + hi) >> 1; if (be[mid] < b) lo = mid + 1; else hi = mid; }
  se[b] = lo;
}

// ---------------- fp32 tiled GEMM v2: 128x128 tile, 8x8/thread ----------------
// C = act(A@W + bias). Dual-output: blocks with bn >= Nsplit use {Wb,bb,Cb}
// (used to fuse the K and V projections: one pass over A, 768 balanced blocks).
// Physical N (row stride of W and C) == Nsplit for all our calls.
// Thread (tx=tid&15, ty=tid>>4) owns rows {ty*4+i, 64+ty*4+i} x cols
// {tx*4+j, 64+tx*4+j} -> per kk: 4 LDS b128 reads (broadcast / 2-way, free)
// feeding 64 FMA -> ~6:1 FMA:LDS issue-cycle ratio (old 64x64 tile was 4:3).
// All register arrays fully unrolled, compile-time indexed (rule #20).
template<int ACT>
__global__ __launch_bounds__(256) void gemm_kernel(
    const float* __restrict__ A,
    const float* __restrict__ Wa, const float* __restrict__ ba, float* __restrict__ Ca,
    const float* __restrict__ Wb, const float* __restrict__ bb, float* __restrict__ Cb,
    int M, int K, int Nsplit) {
  __shared__ float As[16][132];   // transposed A tile, pad 132
  __shared__ float Ws[16][132];
  int bm = blockIdx.y * 128;
  int bn = blockIdx.x * 128;
  const float* W = Wa; const float* bias = ba; float* C = Ca;
  if (bn >= Nsplit) { W = Wb; bias = bb; C = Cb; bn -= Nsplit; }
  const int N = Nsplit;
  int tid = threadIdx.x;
  int tx = tid & 15, ty = tid >> 4;

  float bias0[4], bias1[4];
  *(float4*)bias0 = *(const float4*)&bias[bn + tx * 4];
  *(float4*)bias1 = *(const float4*)&bias[bn + 64 + tx * 4];

  float acc[2][2][4][4] = {};

  int ar  = tid >> 1;            // 0..127
  int acb = (tid & 1) * 8;       // 0 or 8
  int wr  = tid >> 4;            // 0..15
  int wcb = (tid & 15) * 8;      // 0..120

  for (int k0 = 0; k0 < K; k0 += 16) {
    {
      int gr = bm + ar;
      float4 a0 = make_float4(0.f, 0.f, 0.f, 0.f), a1 = a0;
      if (gr < M) {
        const float* ap = &A[(size_t)gr * K + k0 + acb];
        a0 = *(const float4*)ap; a1 = *(const float4*)(ap + 4);
      }
      As[acb + 0][ar] = a0.x; As[acb + 1][ar] = a0.y;
      As[acb + 2][ar] = a0.z; As[acb + 3][ar] = a0.w;
      As[acb + 4][ar] = a1.x; As[acb + 5][ar] = a1.y;
      As[acb + 6][ar] = a1.z; As[acb + 7][ar] = a1.w;
    }
    {
      const float* wp = &W[(size_t)(k0 + wr) * N + bn + wcb];
      *(float4*)&Ws[wr][wcb]     = *(const float4*)wp;
      *(float4*)&Ws[wr][wcb + 4] = *(const float4*)(wp + 4);
    }
    __syncthreads();
#pragma unroll
    for (int kk = 0; kk < 16; ++kk) {
      float a[2][4], w[2][4];
      *(float4*)a[0] = *(const float4*)&As[kk][ty * 4];
      *(float4*)a[1] = *(const float4*)&As[kk][64 + ty * 4];
      *(float4*)w[0] = *(const float4*)&Ws[kk][tx * 4];
      *(float4*)w[1] = *(const float4*)&Ws[kk][64 + tx * 4];
#pragma unroll
      for (int rh = 0; rh < 2; ++rh)
#pragma unroll
        for (int i = 0; i < 4; ++i) {
          float av = a[rh][i];
#pragma unroll
          for (int ch = 0; ch < 2; ++ch)
#pragma unroll
            for (int jj = 0; jj < 4; ++jj)
              acc[rh][ch][i][jj] += av * w[ch][jj];
        }
    }
    __syncthreads();
  }

#pragma unroll
  for (int rh = 0; rh < 2; ++rh)
#pragma unroll
    for (int i = 0; i < 4; ++i) {
      int gr = bm + rh * 64 + ty * 4 + i;
      if (gr >= M) continue;
#pragma unroll
      for (int ch = 0; ch < 2; ++ch) {
        float o[4];
#pragma unroll
        for (int jj = 0; jj < 4; ++jj) {
          float vv = acc[rh][ch][i][jj] + (ch ? bias1[jj] : bias0[jj]);
          if (ACT == 1) vv = 0.5f * vv * (1.0f + erff(vv * 0.70710678118654752f));
          o[jj] = vv;
        }
        *(float4*)&C[(size_t)gr * N + bn + ch * 64 + tx * 4] = *(float4*)o;
      }
    }
}

// ---------------- LayerNorm over last dim (256), in-place ----------------
__global__ __launch_bounds__(256) void ln_kernel(float* __restrict__ h,
    const float* __restrict__ w, const float* __restrict__ b, int M) {
  int row = blockIdx.x * 4 + (threadIdx.x >> 6);
  int lane = threadIdx.x & 63;
  if (row >= M) return;
  float4 v = *(const float4*)&h[(size_t)row * C_DIM + lane * 4];
  float s  = v.x + v.y + v.z + v.w;
  float s2 = v.x * v.x + v.y * v.y + v.z * v.z + v.w * v.w;
#pragma unroll
  for (int off = 1; off < 64; off <<= 1) { s += __shfl_xor(s, off); s2 += __shfl_xor(s2, off); }
  float mu  = s  * (1.0f / 256.0f);
  float var = s2 * (1.0f / 256.0f) - mu * mu;
  float inv = rsqrtf(var + 1e-5f);
  float4 wv = *(const float4*)&w[lane * 4];
  float4 bv = *(const float4*)&b[lane * 4];
  float4 o;
  o.x = (v.x - mu) * inv * wv.x + bv.x;
  o.y = (v.y - mu) * inv * wv.y + bv.y;
  o.z = (v.z - mu) * inv * wv.z + bv.z;
  o.w = (v.w - mu) * inv * wv.w + bv.w;
  *(float4*)&h[(size_t)row * C_DIM + lane * 4] = o;
}

// ---------------- ragged masked flash attention (v5, unchanged) ----------------
// 1 q-row/thread, 32-row q-tiles, 16/bh, grid 8192, XCD-swizzled.
// Measured R4: VGPR 52, occ 35%, VALUBusy 65%, conflicts ~0, 311 us.
__global__ __launch_bounds__(256, 4) void attn_kernel(const float* __restrict__ q,
    const float* __restrict__ k, const float* __restrict__ v,
    const int* __restrict__ sx, const int* __restrict__ se,
    const int* __restrict__ emask, float* __restrict__ y) {
  int bid = blockIdx.x;
  int work = ((bid & 7) << 10) + (bid >> 3);   // same (b,hd) -> same XCD
  int qt = work & 15;
  int bh = work >> 4;
  int b  = bh & 63;
  int hd = bh >> 6;

  int xs = sx[b], lx = sx[b + 1] - xs;
  if (qt * 32 >= lx) return;
  int es = se[b], le = se[b + 1] - es;

  __shared__ float Ks[64][36];
  __shared__ float Vs[64][36];
  __shared__ float Ps[32][68];
  __shared__ float Bs[64];

  int tid = threadIdx.x;
  int j  = tid & 7;
  int qg = tid >> 3;   // 0..31

  int qr = qt * 32 + qg;
  bool qok = qr < lx;
  float qreg[32];
  {
    const float* qp = &q[(size_t)(xs + (qok ? qr : 0)) * C_DIM + hd * HDIM];
#pragma unroll
    for (int d4 = 0; d4 < 8; ++d4) {
      float4 t4 = *(const float4*)&qp[d4 * 4];
      qreg[d4 * 4 + 0] = t4.x; qreg[d4 * 4 + 1] = t4.y;
      qreg[d4 * 4 + 2] = t4.z; qreg[d4 * 4 + 3] = t4.w;
    }
  }

  float acc[4] = {};
  float mrun = -INFINITY, lrun = 0.f;
  const float scale = 0.17677669529663689f;  // 1/sqrt(32)

  for (int kc = 0; kc < le; kc += 64) {
    int nk = le - kc; if (nk > 64) nk = 64;
    {
      int r = tid >> 3, c = (tid & 7) * 4;
#pragma unroll
      for (int it = 0; it < 2; ++it) {
        int rr = r + it * 32;
        float4 kv = make_float4(0.f, 0.f, 0.f, 0.f);
        float4 vv = make_float4(0.f, 0.f, 0.f, 0.f);
        if (rr < nk) {
          size_t base = (size_t)(es + kc + rr) * C_DIM + hd * HDIM + c;
          kv = *(const float4*)&k[base];
          vv = *(const float4*)&v[base];
        }
        *(float4*)&Ks[rr][c] = kv;
        *(float4*)&Vs[rr][c] = vv;
      }
      if (tid < 64)
        Bs[tid] = (tid < nk && emask[es + kc + tid]) ? 0.f : -1e30f;
    }
    __syncthreads();

    float bs[8];
#pragma unroll
    for (int t = 0; t < 8; ++t) bs[t] = Bs[t * 8 + j];

    float p[8];
#pragma unroll
    for (int t = 0; t < 8; ++t) {
      const float* krow = &Ks[t * 8 + j][0];
      float s = 0.f;
#pragma unroll
      for (int d4 = 0; d4 < 8; ++d4) {
        float4 kv = *(const float4*)&krow[d4 * 4];
        s += qreg[d4 * 4 + 0] * kv.x + qreg[d4 * 4 + 1] * kv.y
           + qreg[d4 * 4 + 2] * kv.z + qreg[d4 * 4 + 3] * kv.w;
      }
      p[t] = s * scale + bs[t];
    }

    float mloc = p[0];
#pragma unroll
    for (int t = 1; t < 8; ++t) mloc = fmaxf(mloc, p[t]);
    mloc = fmaxf(mloc, __shfl_xor(mloc, 1));
    mloc = fmaxf(mloc, __shfl_xor(mloc, 2));
    mloc = fmaxf(mloc, __shfl_xor(mloc, 4));
    float mnew = fmaxf(mrun, mloc);
    float alpha = __expf(mrun - mnew);
    float lloc = 0.f;
#pragma unroll
    for (int t = 0; t < 8; ++t) {
      float pe = __expf(p[t] - mnew);
      Ps[qg][t * 8 + j] = pe;
      lloc += pe;
    }
    lloc += __shfl_xor(lloc, 1);
    lloc += __shfl_xor(lloc, 2);
    lloc += __shfl_xor(lloc, 4);
    lrun = lrun * alpha + lloc;
    mrun = mnew;
#pragma unroll
    for (int d = 0; d < 4; ++d) acc[d] *= alpha;

#pragma unroll
    for (int kk4 = 0; kk4 < 16; ++kk4) {
      float pa[4];
      *(float4*)pa = *(const float4*)&Ps[qg][kk4 * 4];
#pragma unroll
      for (int u = 0; u < 4; ++u) {
        float4 vv = *(const float4*)&Vs[kk4 * 4 + u][j * 4];
        acc[0] += pa[u] * vv.x; acc[1] += pa[u] * vv.y;
        acc[2] += pa[u] * vv.z; acc[3] += pa[u] * vv.w;
      }
    }
    __syncthreads();
  }

  if (qok) {
    float invl = (lrun > 0.f) ? 1.0f / lrun : 0.f;
    float4 o = make_float4(acc[0] * invl, acc[1] * invl,
                           acc[2] * invl, acc[3] * invl);
    *(float4*)&y[(size_t)(xs + qr) * C_DIM + hd * HDIM + j * 4] = o;
  }
}

// ---------------- launch ----------------
extern "C" void kernel_launch(void* const* d_in, const int* in_sizes, int n_in,
                              void* d_out, int out_size, void* d_ws, size_t ws_size,
                              hipStream_t stream) {
  const float* x    = (const float*)d_in[0];
  const int*   bx   = (const int*)d_in[1];
  const int*   be   = (const int*)d_in[2];
  const float* enc  = (const float*)d_in[3];
  const int*   msk  = (const int*)d_in[4];
  const float* Wq   = (const float*)d_in[5];
  const float* bq   = (const float*)d_in[6];
  const float* Wk   = (const float*)d_in[7];
  const float* bk   = (const float*)d_in[8];
  const float* Wv   = (const float*)d_in[9];
  const float* bv   = (const float*)d_in[10];
  const float* Wp   = (const float*)d_in[11];
  const float* bp   = (const float*)d_in[12];
  const float* W1   = (const float*)d_in[13];
  const float* b1   = (const float*)d_in[14];
  const float* W2   = (const float*)d_in[15];
  const float* b2   = (const float*)d_in[16];
  const float* lnw  = (const float*)d_in[17];
  const float* lnb  = (const float*)d_in[18];
  float* out = (float*)d_out;

  int Nx = in_sizes[0] / C_DIM;
  int Ne = in_sizes[3] / IN_DIM;
  int maxN = Nx > Ne ? Nx : Ne;

  char* ws = (char*)d_ws;
  int* sx = (int*)ws;          // 65 ints
  int* se = sx + 80;           // 65 ints
  float* R0 = (float*)(ws + 4096);              // Ne*512 floats (g, later k|v)
  float* g    = R0;
  float* kbuf = R0;
  float* vbuf = R0 + (size_t)Ne * C_DIM;
  float* R1 = R0 + (size_t)Ne * EMB_DIM;        // maxN*256 floats (h, later y)
  float* h    = R1;
  float* ybuf = R1;
  float* qbuf = R1 + (size_t)maxN * C_DIM;      // Nx*256 floats

  starts_kernel<<<1, 128, 0, stream>>>(bx, Nx, be, Ne, sx, se);

  int gyE = (Ne + 127) / 128;   // 192
  int gyX = (Nx + 127) / 128;   // 192

  // MLP: g = GELU(enc @ W1 + b1)   [Ne,512]
  gemm_kernel<1><<<dim3(EMB_DIM / 128, gyE), 256, 0, stream>>>(
      enc, W1, b1, g, W1, b1, g, Ne, IN_DIM, EMB_DIM);
  // h = g @ W2 + b2  [Ne,256], then LN
  gemm_kernel<0><<<dim3(C_DIM / 128, gyE), 256, 0, stream>>>(
      g, W2, b2, h, W2, b2, h, Ne, EMB_DIM, C_DIM);
  ln_kernel<<<(Ne + 3) / 4, 256, 0, stream>>>(h, lnw, lnb, Ne);

  // q = x @ Wq + bq
  gemm_kernel<0><<<dim3(C_DIM / 128, gyX), 256, 0, stream>>>(
      x, Wq, bq, qbuf, Wq, bq, qbuf, Nx, C_DIM, C_DIM);
  // fused: k = h @ Wk + bk ; v = h @ Wv + bv  (one A pass, 768 balanced blocks)
  gemm_kernel<0><<<dim3(2 * C_DIM / 128, gyE), 256, 0, stream>>>(
      h, Wk, bk, kbuf, Wv, bv, vbuf, Ne, C_DIM, C_DIM);

  // attention -> ybuf (overwrites h region; h dead after k,v)
  attn_kernel<<<dim3(8192), 256, 0, stream>>>(
      qbuf, kbuf, vbuf, sx, se, msk, ybuf);

  // out = y @ Wp + bp
  gemm_kernel<0><<<dim3(C_DIM / 128, gyX), 256, 0, stream>>>(
      ybuf, Wp, bp, out, Wp, bp, out, Nx, C_DIM, C_DIM);
}